// Round 4
// baseline (142.328 us; speedup 1.0000x reference)
//
#include <hip/hip_runtime.h>

#define NGRAPH 128
#define NBLK   2048
#define BS     256

// d_ws layout: [0, 1KB)  = acc[256]  (sums 0..127, counts 128..255)
//              [1KB, ..) = packed float4 per node {x, y, gid_bits, 0}

__global__ __launch_bounds__(BS) void edgevar_pack(
    const float2* __restrict__ pos,
    const int*    __restrict__ batch,
    float4*       __restrict__ packed,
    float*        __restrict__ acc,
    int N) {
  const int i = blockIdx.x * BS + threadIdx.x;
  if (blockIdx.x == 0 && threadIdx.x < 2 * NGRAPH) acc[threadIdx.x] = 0.f;
  if (i < N) {
    float2 p = pos[i];
    packed[i] = make_float4(p.x, p.y, __int_as_float(batch[i]), 0.f);
  }
}

__global__ __launch_bounds__(BS) void edgevar_stage1(
    const float4* __restrict__ packed,
    const int*    __restrict__ ei,
    float*        __restrict__ acc,
    int E) {
  __shared__ float s_acc[2 * NGRAPH];
  if (threadIdx.x < 2 * NGRAPH) s_acc[threadIdx.x] = 0.f;
  __syncthreads();

  const int tid = blockIdx.x * BS + threadIdx.x;
  const int nth = NBLK * BS;
  const int E4  = E >> 2;
  const int4*   __restrict__ s4  = (const int4*)ei;
  const int4*   __restrict__ d4  = (const int4*)(ei + E);
  const float2* __restrict__ pp2 = (const float2*)packed;  // pp2[2*i] = {x,y}

  for (int i = tid; i < E4; i += nth) {
    int4 s = s4[i];
    int4 d = d4[i];
    int ss[4] = {s.x, s.y, s.z, s.w};
    int dd[4] = {d.x, d.y, d.z, d.w};
#pragma unroll
    for (int k = 0; k < 4; ++k) {
      float4 a = packed[ss[k]];          // one 16B txn: pos + gid
      float2 b = pp2[2 * dd[k]];         // one 8B txn: pos only
      float dx = b.x - a.x, dy = b.y - a.y;
      float eu = sqrtf(dx * dx + dy * dy);
      float v  = eu - 1.f;
      v *= v;
      int g = __float_as_int(a.z);
      atomicAdd(&s_acc[g], v);
      atomicAdd(&s_acc[NGRAPH + g], 1.f);
    }
  }
  // tail (E not divisible by 4) — E=3.2M is divisible, kept for safety
  for (int e = (E4 << 2) + tid; e < E; e += nth) {
    float4 a = packed[ei[e]];
    float2 b = pp2[2 * ei[e + E]];
    float dx = b.x - a.x, dy = b.y - a.y;
    float eu = sqrtf(dx * dx + dy * dy);
    float v  = eu - 1.f;
    v *= v;
    int g = __float_as_int(a.z);
    atomicAdd(&s_acc[g], v);
    atomicAdd(&s_acc[NGRAPH + g], 1.f);
  }

  __syncthreads();
  if (threadIdx.x < 2 * NGRAPH) {
    float v = s_acc[threadIdx.x];
    atomicAdd(&acc[threadIdx.x], v);   // one atomic per block per slot
  }
}

__global__ __launch_bounds__(64) void edgevar_finalize(
    const float* __restrict__ acc,
    float*       __restrict__ out) {
  const int t = threadIdx.x;  // 64 threads, 1 wave
  float v = acc[t]      / fmaxf(acc[128 + t], 1.f)
          + acc[t + 64] / fmaxf(acc[192 + t], 1.f);
  for (int off = 32; off; off >>= 1) v += __shfl_down(v, off);
  if (t == 0) out[0] = v * (1.0f / NGRAPH);
}

extern "C" void kernel_launch(void* const* d_in, const int* in_sizes, int n_in,
                              void* d_out, int out_size, void* d_ws, size_t ws_size,
                              hipStream_t stream) {
  const float2* pos   = (const float2*)d_in[0];
  const int*    ei    = (const int*)d_in[1];
  const int*    batch = (const int*)d_in[2];
  float*        out   = (float*)d_out;
  float*        acc    = (float*)d_ws;
  float4*       packed = (float4*)((char*)d_ws + 1024);
  const int N = in_sizes[0] / 2;
  const int E = in_sizes[1] / 2;

  hipLaunchKernelGGL(edgevar_pack, dim3((N + BS - 1) / BS), dim3(BS), 0, stream,
                     pos, batch, packed, acc, N);
  hipLaunchKernelGGL(edgevar_stage1, dim3(NBLK), dim3(BS), 0, stream,
                     packed, ei, acc, E);
  hipLaunchKernelGGL(edgevar_finalize, dim3(1), dim3(64), 0, stream,
                     acc, out);
}

// Round 5
// 120.466 us; speedup vs baseline: 1.1815x; 1.1815x over previous
//
#include <hip/hip_runtime.h>

#define NGRAPH 128
#define NBLK   1024
#define BS     256

// d_ws layout: [0, N*16)            packed float4 per node {x, y, gid_bits, 0}
//              [N*16, N*16 + 1MB)   part[NBLK][256] block partials

__global__ __launch_bounds__(BS) void edgevar_pack(
    const float2* __restrict__ pos,
    const int*    __restrict__ batch,
    float4*       __restrict__ packed,
    int N) {
  const int i = blockIdx.x * BS + threadIdx.x;
  if (i < N) {
    float2 p = pos[i];
    packed[i] = make_float4(p.x, p.y, __int_as_float(batch[i]), 0.f);
  }
}

__global__ __launch_bounds__(BS) void edgevar_stage1(
    const float4* __restrict__ packed,
    const int*    __restrict__ ei,
    float*        __restrict__ part,
    int E) {
  __shared__ float s_acc[2 * NGRAPH];   // [0,128) sums, [128,256) counts
  s_acc[threadIdx.x] = 0.f;             // BS == 2*NGRAPH == 256
  __syncthreads();

  const int tid = blockIdx.x * BS + threadIdx.x;
  const int nth = NBLK * BS;
  const int E4  = E >> 2;
  const int4*   __restrict__ s4  = (const int4*)ei;
  const int4*   __restrict__ d4  = (const int4*)(ei + E);
  const float2* __restrict__ pp2 = (const float2*)packed;  // pp2[2*i] = {x,y}

  for (int i = tid; i < E4; i += nth) {
    int4 s = s4[i];
    int4 d = d4[i];
    int ss[4] = {s.x, s.y, s.z, s.w};
    int dd[4] = {d.x, d.y, d.z, d.w};
#pragma unroll
    for (int k = 0; k < 4; ++k) {
      float4 a = packed[ss[k]];          // 16B txn: pos + gid
      float2 b = pp2[2 * dd[k]];         // 8B txn: pos
      float dx = b.x - a.x, dy = b.y - a.y;
      float eu = sqrtf(dx * dx + dy * dy);
      float v  = eu - 1.f;
      v *= v;
      int g = __float_as_int(a.z);
      atomicAdd(&s_acc[g], v);           // LDS atomic — cheap
      atomicAdd(&s_acc[NGRAPH + g], 1.f);
    }
  }
  for (int e = (E4 << 2) + tid; e < E; e += nth) {   // tail safety
    float4 a = packed[ei[e]];
    float2 b = pp2[2 * ei[e + E]];
    float dx = b.x - a.x, dy = b.y - a.y;
    float eu = sqrtf(dx * dx + dy * dy);
    float v  = eu - 1.f;
    v *= v;
    int g = __float_as_int(a.z);
    atomicAdd(&s_acc[g], v);
    atomicAdd(&s_acc[NGRAPH + g], 1.f);
  }

  __syncthreads();
  // one coalesced non-atomic 1KB store per block — NO global atomics
  part[(size_t)blockIdx.x * (2 * NGRAPH) + threadIdx.x] = s_acc[threadIdx.x];
}

__global__ __launch_bounds__(1024) void edgevar_stage2(
    const float* __restrict__ part,
    float*       __restrict__ out) {
  const int t    = threadIdx.x;
  const int slot = t & 255;
  const int rc   = t >> 8;                      // 0..3 row-chunks
  const int ROWS = NBLK / 4;

  float acc = 0.f;
  const float* p = part + (size_t)rc * ROWS * 256 + slot;
#pragma unroll 8
  for (int r = 0; r < ROWS; ++r) acc += p[(size_t)r * 256];

  __shared__ float s1[1024];
  s1[t] = acc;
  __syncthreads();

  __shared__ float s2[256];
  if (t < 256) s2[t] = s1[t] + s1[t + 256] + s1[t + 512] + s1[t + 768];
  __syncthreads();

  __shared__ float var[NGRAPH];
  if (t < NGRAPH) var[t] = s2[t] / fmaxf(s2[NGRAPH + t], 1.f);
  __syncthreads();

  if (t < 64) {
    float v = var[t] + var[t + 64];
    for (int off = 32; off; off >>= 1) v += __shfl_down(v, off);
    if (t == 0) out[0] = v * (1.0f / NGRAPH);
  }
}

extern "C" void kernel_launch(void* const* d_in, const int* in_sizes, int n_in,
                              void* d_out, int out_size, void* d_ws, size_t ws_size,
                              hipStream_t stream) {
  const float2* pos   = (const float2*)d_in[0];
  const int*    ei    = (const int*)d_in[1];
  const int*    batch = (const int*)d_in[2];
  float*        out   = (float*)d_out;
  const int N = in_sizes[0] / 2;
  const int E = in_sizes[1] / 2;

  float4* packed = (float4*)d_ws;
  float*  part   = (float*)((char*)d_ws + (size_t)N * sizeof(float4));

  hipLaunchKernelGGL(edgevar_pack, dim3((N + BS - 1) / BS), dim3(BS), 0, stream,
                     pos, batch, packed, N);
  hipLaunchKernelGGL(edgevar_stage1, dim3(NBLK), dim3(BS), 0, stream,
                     packed, ei, part, E);
  hipLaunchKernelGGL(edgevar_stage2, dim3(1), dim3(1024), 0, stream,
                     part, out);
}

// Round 6
// 116.046 us; speedup vs baseline: 1.2265x; 1.0381x over previous
//
#include <hip/hip_runtime.h>

#define NGRAPH 128
#define NBLK   1024
#define BS     256

// Fixed-point packing: one u64 per (sum,count) pair.
//   bits [0,42)  : sum of edge_var scaled by 2^18  (worst case ~2^40)
//   bits [42,64) : edge count (max 3.2M < 2^22)
#define FIX_SCALE 262144.0f          // 2^18
#define CNT_SHIFT 42

// d_ws layout: [0, N*16)          packed float4 per node {x, y, gid_bits, 0}
//              [N*16, +1MB)       part[NBLK][128] u64 block partials

__global__ __launch_bounds__(BS) void edgevar_pack(
    const float2* __restrict__ pos,
    const int*    __restrict__ batch,
    float4*       __restrict__ packed,
    int N) {
  const int i = blockIdx.x * BS + threadIdx.x;
  if (i < N) {
    float2 p = pos[i];
    packed[i] = make_float4(p.x, p.y, __int_as_float(batch[i]), 0.f);
  }
}

__global__ __launch_bounds__(BS) void edgevar_stage1(
    const float4* __restrict__ packed,
    const int*    __restrict__ ei,
    unsigned long long* __restrict__ part,
    int E) {
  __shared__ unsigned long long s_acc[4][NGRAPH];   // 4-way privatized, 4KB
  {
    unsigned long long* f = &s_acc[0][0];
    if (threadIdx.x < 2 * NGRAPH) {
      f[threadIdx.x] = 0ull;
      f[threadIdx.x + 2 * NGRAPH] = 0ull;
    }
  }
  __syncthreads();

  const int cp  = threadIdx.x & 3;
  const int tid = blockIdx.x * BS + threadIdx.x;
  const int nth = NBLK * BS;
  const int E4  = E >> 2;
  const int4*   __restrict__ s4  = (const int4*)ei;
  const int4*   __restrict__ d4  = (const int4*)(ei + E);
  const float2* __restrict__ pp2 = (const float2*)packed;

  for (int i = tid; i < E4; i += nth) {
    int4 s = s4[i];
    int4 d = d4[i];
    int ss[4] = {s.x, s.y, s.z, s.w};
    int dd[4] = {d.x, d.y, d.z, d.w};
#pragma unroll
    for (int k = 0; k < 4; ++k) {
      float4 a = packed[ss[k]];          // 16B txn: pos + gid
      float2 b = pp2[2 * dd[k]];         // 8B txn: pos
      float dx = b.x - a.x, dy = b.y - a.y;
      float v  = sqrtf(dx * dx + dy * dy) - 1.f;
      v *= v;
      int g = __float_as_int(a.z);
      unsigned long long contrib =
          (1ull << CNT_SHIFT) | (unsigned long long)(v * FIX_SCALE + 0.5f);
      atomicAdd(&s_acc[cp][g], contrib);   // single LDS atomic per edge
    }
  }
  for (int e = (E4 << 2) + tid; e < E; e += nth) {   // tail safety
    float4 a = packed[ei[e]];
    float2 b = pp2[2 * ei[e + E]];
    float dx = b.x - a.x, dy = b.y - a.y;
    float v  = sqrtf(dx * dx + dy * dy) - 1.f;
    v *= v;
    int g = __float_as_int(a.z);
    unsigned long long contrib =
        (1ull << CNT_SHIFT) | (unsigned long long)(v * FIX_SCALE + 0.5f);
    atomicAdd(&s_acc[cp][g], contrib);
  }

  __syncthreads();
  if (threadIdx.x < NGRAPH) {
    unsigned long long t = s_acc[0][threadIdx.x] + s_acc[1][threadIdx.x]
                         + s_acc[2][threadIdx.x] + s_acc[3][threadIdx.x];
    part[(size_t)blockIdx.x * NGRAPH + threadIdx.x] = t;   // coalesced, no atomics
  }
}

__global__ __launch_bounds__(1024) void edgevar_stage2(
    const unsigned long long* __restrict__ part,
    float* __restrict__ out) {
  const int t    = threadIdx.x;
  const int slot = t & (NGRAPH - 1);
  const int rc   = t >> 7;                 // 0..7 row-chunks
  const int ROWS = NBLK / 8;

  unsigned long long acc = 0ull;           // exact integer accumulation
  const unsigned long long* p = part + (size_t)rc * ROWS * NGRAPH + slot;
#pragma unroll 8
  for (int r = 0; r < ROWS; ++r) acc += p[(size_t)r * NGRAPH];

  __shared__ unsigned long long s[1024];
  s[t] = acc;
  __syncthreads();

  __shared__ float var[NGRAPH];
  if (t < NGRAPH) {
    unsigned long long tot = 0ull;
#pragma unroll
    for (int j = 0; j < 8; ++j) tot += s[t + NGRAPH * j];
    unsigned int       cnt = (unsigned int)(tot >> CNT_SHIFT);
    unsigned long long fx  = tot & ((1ull << CNT_SHIFT) - 1ull);
    float sum = (float)fx * (1.0f / FIX_SCALE);
    var[t] = sum / fmaxf((float)cnt, 1.f);
  }
  __syncthreads();

  if (t < 64) {
    float v = var[t] + var[t + 64];
    for (int off = 32; off; off >>= 1) v += __shfl_down(v, off);
    if (t == 0) out[0] = v * (1.0f / NGRAPH);
  }
}

extern "C" void kernel_launch(void* const* d_in, const int* in_sizes, int n_in,
                              void* d_out, int out_size, void* d_ws, size_t ws_size,
                              hipStream_t stream) {
  const float2* pos   = (const float2*)d_in[0];
  const int*    ei    = (const int*)d_in[1];
  const int*    batch = (const int*)d_in[2];
  float*        out   = (float*)d_out;
  const int N = in_sizes[0] / 2;
  const int E = in_sizes[1] / 2;

  float4*             packed = (float4*)d_ws;
  unsigned long long* part   =
      (unsigned long long*)((char*)d_ws + (size_t)N * sizeof(float4));

  hipLaunchKernelGGL(edgevar_pack, dim3((N + BS - 1) / BS), dim3(BS), 0, stream,
                     pos, batch, packed, N);
  hipLaunchKernelGGL(edgevar_stage1, dim3(NBLK), dim3(BS), 0, stream,
                     packed, ei, part, E);
  hipLaunchKernelGGL(edgevar_stage2, dim3(1), dim3(1024), 0, stream,
                     part, out);
}

// Round 8
// 105.419 us; speedup vs baseline: 1.3501x; 1.1008x over previous
//
#include <hip/hip_runtime.h>

#define NGRAPH 128
#define NBLK   2048
#define BS     256

// Fixed-point packing: one u64 per (sum,count) pair.
//   bits [0,42)  : sum of edge_var scaled by 2^18  (worst case ~2^40)
//   bits [42,64) : edge count (max 3.2M < 2^22)
#define FIX_SCALE 262144.0f          // 2^18
#define CNT_SHIFT 42

// d_ws layout: [0, N*16)        packed float4 per node {x, y, gid_bits, 0}
//              [+0, +2MB)       part[NGRAPH][NBLK] u64 partials (TRANSPOSED)
//              [+2MB, +512B)    gvar[NGRAPH] float

__global__ __launch_bounds__(BS) void edgevar_pack(
    const float2* __restrict__ pos,
    const int*    __restrict__ batch,
    float4*       __restrict__ packed,
    int N) {
  const int i = blockIdx.x * BS + threadIdx.x;
  if (i < N) {
    float2 p = pos[i];
    packed[i] = make_float4(p.x, p.y, __int_as_float(batch[i]), 0.f);
  }
}

__global__ __launch_bounds__(BS) void edgevar_stage1(
    const float4* __restrict__ packed,
    const int*    __restrict__ ei,
    unsigned long long* __restrict__ part,
    int E) {
  __shared__ unsigned long long s_acc[4][NGRAPH];   // 4-way privatized, 4KB
  {
    unsigned long long* f = &s_acc[0][0];
    if (threadIdx.x < 2 * NGRAPH) {
      f[threadIdx.x] = 0ull;
      f[threadIdx.x + 2 * NGRAPH] = 0ull;
    }
  }
  __syncthreads();

  const int cp  = threadIdx.x & 3;
  const int tid = blockIdx.x * BS + threadIdx.x;
  const int nth = NBLK * BS;
  const int E4  = E >> 2;
  const int4*   __restrict__ s4  = (const int4*)ei;
  const int4*   __restrict__ d4  = (const int4*)(ei + E);
  const float2* __restrict__ pp2 = (const float2*)packed;

  for (int i = tid; i < E4; i += nth) {
    int4 s = s4[i];
    int4 d = d4[i];
    int ss[4] = {s.x, s.y, s.z, s.w};
    int dd[4] = {d.x, d.y, d.z, d.w};
#pragma unroll
    for (int k = 0; k < 4; ++k) {
      float4 a = packed[ss[k]];          // 16B txn: pos + gid
      float2 b = pp2[2 * dd[k]];         // 8B txn: pos
      float dx = b.x - a.x, dy = b.y - a.y;
      float v  = sqrtf(dx * dx + dy * dy) - 1.f;
      v *= v;
      int g = __float_as_int(a.z);
      unsigned long long contrib =
          (1ull << CNT_SHIFT) | (unsigned long long)(v * FIX_SCALE + 0.5f);
      atomicAdd(&s_acc[cp][g], contrib);   // single LDS atomic per edge
    }
  }
  for (int e = (E4 << 2) + tid; e < E; e += nth) {   // tail safety
    float4 a = packed[ei[e]];
    float2 b = pp2[2 * ei[e + E]];
    float dx = b.x - a.x, dy = b.y - a.y;
    float v  = sqrtf(dx * dx + dy * dy) - 1.f;
    v *= v;
    int g = __float_as_int(a.z);
    unsigned long long contrib =
        (1ull << CNT_SHIFT) | (unsigned long long)(v * FIX_SCALE + 0.5f);
    atomicAdd(&s_acc[cp][g], contrib);
  }

  __syncthreads();
  if (threadIdx.x < NGRAPH) {
    unsigned long long t = s_acc[0][threadIdx.x] + s_acc[1][threadIdx.x]
                         + s_acc[2][threadIdx.x] + s_acc[3][threadIdx.x];
    // transposed: part[slot][block] — scattered 8B stores (128/block, cheap),
    // makes stage2 row-contiguous
    part[(size_t)threadIdx.x * NBLK + blockIdx.x] = t;
  }
}

__global__ __launch_bounds__(BS) void edgevar_stage2(
    const unsigned long long* __restrict__ part,
    float* __restrict__ gvar) {
  const int g = blockIdx.x;          // one block per graph
  const int t = threadIdx.x;
  const unsigned long long* row = part + (size_t)g * NBLK;
  unsigned long long acc = 0ull;     // exact integer accumulation
#pragma unroll
  for (int k = 0; k < NBLK / BS; ++k) acc += row[t + k * BS];
  for (int off = 32; off; off >>= 1) acc += __shfl_down(acc, off);
  __shared__ unsigned long long wsum[4];
  if ((t & 63) == 0) wsum[t >> 6] = acc;
  __syncthreads();
  if (t == 0) {
    unsigned long long tot = wsum[0] + wsum[1] + wsum[2] + wsum[3];
    unsigned int       cnt = (unsigned int)(tot >> CNT_SHIFT);
    float sum = (float)(tot & ((1ull << CNT_SHIFT) - 1ull)) * (1.0f / FIX_SCALE);
    gvar[g] = sum / fmaxf((float)cnt, 1.f);
  }
}

__global__ __launch_bounds__(64) void edgevar_stage3(
    const float* __restrict__ gvar,
    float*       __restrict__ out) {
  const int t = threadIdx.x;
  float v = gvar[t] + gvar[t + 64];
  for (int off = 32; off; off >>= 1) v += __shfl_down(v, off);
  if (t == 0) out[0] = v * (1.0f / NGRAPH);
}

extern "C" void kernel_launch(void* const* d_in, const int* in_sizes, int n_in,
                              void* d_out, int out_size, void* d_ws, size_t ws_size,
                              hipStream_t stream) {
  const float2* pos   = (const float2*)d_in[0];
  const int*    ei    = (const int*)d_in[1];
  const int*    batch = (const int*)d_in[2];
  float*        out   = (float*)d_out;
  const int N = in_sizes[0] / 2;
  const int E = in_sizes[1] / 2;

  float4*             packed = (float4*)d_ws;
  unsigned long long* part   =
      (unsigned long long*)((char*)d_ws + (size_t)N * sizeof(float4));
  float* gvar = (float*)((char*)part + (size_t)NGRAPH * NBLK * sizeof(unsigned long long));

  hipLaunchKernelGGL(edgevar_pack, dim3((N + BS - 1) / BS), dim3(BS), 0, stream,
                     pos, batch, packed, N);
  hipLaunchKernelGGL(edgevar_stage1, dim3(NBLK), dim3(BS), 0, stream,
                     packed, ei, part, E);
  hipLaunchKernelGGL(edgevar_stage2, dim3(NGRAPH), dim3(BS), 0, stream,
                     part, gvar);
  hipLaunchKernelGGL(edgevar_stage3, dim3(1), dim3(64), 0, stream,
                     gvar, out);
}